// Round 13
// baseline (445.383 us; speedup 1.0000x reference)
//
#include <hip/hip_runtime.h>
#include <hip/hip_bf16.h>

// ---------------------------------------------------------------------------
// RNN_17214228922840: GraphRNN-ish model. fp32 I/O, bf16 MFMA compute.
//   B=128, TV=32, TE=64, VOCAB=1024, EMB=256, H=512 (3H=1536), REPR=128, NET=8
// Outputs (flat, fp32): O_vertex [128,1024,32] | O_edge [128,32,2,64] | O_edge_type [128,8,64]
// h row space b-major: row = b*T + t.   gi row space t-major: row = t*128 + b.
//
// R13 = R12 + prep kernel eliminated (weights converted inside fused_scan).
// Ledger: R12 ran 434.9 (fused 336.8). Residual outside the fused kernel
// = 98us for ONLY prep + 1 gap + fixed overhead; cross-checks vs R0/R10 put
// prep at ~50-90us -- it's a 3593-tiny-block launch-bound kernel moving just
// 22MB. Replace it:
//  - hipMemsetAsync zeroes flags+gicnt (1KB) on-stream (capture-safe; the
//    harness reset itself enqueues memsets).
//  - fused_scan blocks 0..255 (the initially-resident set at 1 block/CU)
//    each convert 15 x 1024-elem chunks fp32->bf16 (agent stores ->
//    s_waitcnt(0) -> barrier -> prepdone++ at gicnt[100]).
//  - gru + producer blocks gate_on(prepdone==256) before reading cvt
//    (single-poller; first-touch loads after gate). Consumers/tail gate
//    transitively via vdone/edone. Acyclic; barriers block-uniform.
// Everything else byte-identical to R12 (fused: R5 gru core 0..127, giE
// 128..511, giV 512..703 low-t-first, OV 704..831, vrep 832..847, erep
// 848..879, etype 880..1007, attn 1008..1135; 84KB LDS -> 1 block/CU).
// ---------------------------------------------------------------------------

typedef __bf16 bf16_t;
typedef bf16_t bf16x8 __attribute__((ext_vector_type(8)));
typedef bf16_t bf16x4 __attribute__((ext_vector_type(4)));
typedef float  f32x4  __attribute__((ext_vector_type(4)));
typedef unsigned long long ull_t;

// workspace layout (bf16 element offsets)
#define OFF_GIV  0ull                    // 4096*1536 (t-major)
#define OFF_GIE  6291456ull              // 8192*1536 (t-major)
#define OFF_HV   18874368ull             // 128*32*512 (b-major)
#define OFF_HE   20971520ull             // 128*64*512 (b-major)
#define OFF_VREP 25165824ull             // 128*32*128
#define OFF_EREP 25690112ull             // 128*64*128
#define OFF_HBUF 26738688ull             // 16 slots * 2 parity * 8192 = 262144 elems
#define FLAG_BYTE_OFF  54001664ull       // 16 slots * 8 ints = 512 B (memset-zeroed)
#define GICNT_BYTE_OFF 54002176ull       // 128 ints (memset-zeroed): [0..31] giV,
                                         // [32..95] giE, [96]=vdone, [97]=edone,
                                         // [98]=vrepdone, [99]=erepdone, [100]=prepdone
#define OFF_CVT  27002880ull             // converted bf16 weights below
#define CVT_VEMB  0ull
#define CVT_EEMB  262144ull
#define CVT_VWI   270336ull
#define CVT_EWI   663552ull
#define CVT_VWH   1449984ull
#define CVT_EWH   2236416ull
#define CVT_VOUT  3022848ull
#define CVT_VREPW 3547136ull
#define CVT_EREPW 3612672ull

// output flat offsets (fp32 elements)
#define OUT_OV 0ull
#define OUT_OE 4194304ull
#define OUT_OT 4718592ull

__device__ __forceinline__ float fsigmoid(float x) {
    float e = __builtin_amdgcn_exp2f(-x * 1.4426950408889634f);
    return __builtin_amdgcn_rcpf(1.0f + e);
}
__device__ __forceinline__ float ftanh(float x) {
    x = fminf(x, 15.0f);
    float e = __builtin_amdgcn_exp2f(x * 2.8853900817779268f); // exp(2x)
    return (e - 1.0f) * __builtin_amdgcn_rcpf(e + 1.0f);
}

// ---------------------------------------------------------------------------
// gi producer tile: 8 waves x 64x64, rows t-major (row = t*128 + b). Agent
// stores -> waitcnt -> barrier -> 4 slice-counter adds (R3-validated).
// ---------------------------------------------------------------------------
template<int GATHER, int K>
__device__ __forceinline__ void produce_gi(
    const bf16_t* __restrict__ W, const float* __restrict__ bias,
    bf16_t* __restrict__ C, const int* __restrict__ gidx,
    const bf16_t* __restrict__ emb, int* __restrict__ cnt, int bx, int nbase)
{
    constexpr int K32 = K / 32;
    const int tid = threadIdx.x, lane = tid & 63, wv = tid >> 6;
    const int r16 = lane & 15, quad = lane >> 4, koff = quad * 8;
    const int mbase = bx * 512 + wv * 64;

    const bf16_t* ap0[4];
    const bf16_t* ap1[4];
#pragma unroll
    for (int i = 0; i < 4; ++i) {
        int row = mbase + i * 16 + r16;
        int b = row & 127, t = row >> 7;
        if (GATHER == 1) {
            ap0[i] = emb + (size_t)gidx[b * 32 + t] * 256 + koff;
            ap1[i] = ap0[i];
        } else {
            int c = (b * 64 + t) * 3;
            ap0[i] = emb + (size_t)gidx[c] * 256 + koff;
            ap1[i] = emb + (size_t)gidx[c + 1] * 256 + koff;
        }
    }
    const bf16_t* bp[4];
#pragma unroll
    for (int j = 0; j < 4; ++j)
        bp[j] = W + (size_t)(nbase + j * 16 + r16) * K + koff;

    f32x4 acc[4][4];
#pragma unroll
    for (int i = 0; i < 4; ++i)
#pragma unroll
        for (int j = 0; j < 4; ++j) acc[i][j] = (f32x4){0.f, 0.f, 0.f, 0.f};

    for (int kc = 0; kc < K32; ++kc) {
        bf16x8 a[4], b[4];
#pragma unroll
        for (int i = 0; i < 4; ++i) {
            const bf16_t* p;
            if (GATHER == 2) p = (kc < 8) ? (ap0[i] + kc * 32) : (ap1[i] + (kc - 8) * 32);
            else             p = ap0[i] + kc * 32;
            a[i] = *(const bf16x8*)p;
        }
#pragma unroll
        for (int j = 0; j < 4; ++j) b[j] = *(const bf16x8*)(bp[j] + kc * 32);
#pragma unroll
        for (int i = 0; i < 4; ++i)
#pragma unroll
            for (int j = 0; j < 4; ++j)
                acc[i][j] = __builtin_amdgcn_mfma_f32_16x16x32_bf16(a[i], b[j], acc[i][j], 0, 0, 0);
    }

#pragma unroll
    for (int j = 0; j < 4; ++j) {
        int col = nbase + j * 16 + r16;
        float bf = bias[col];
#pragma unroll
        for (int i = 0; i < 4; ++i) {
#pragma unroll
            for (int q = 0; q < 4; ++q) {
                int row = mbase + i * 16 + quad * 4 + q;
                bf16_t hb = (bf16_t)(acc[i][j][q] + bf);
                __hip_atomic_store((unsigned short*)(C + (size_t)row * 1536 + col),
                                   __builtin_bit_cast(unsigned short, hb),
                                   __ATOMIC_RELAXED, __HIP_MEMORY_SCOPE_AGENT);
            }
        }
    }
    __builtin_amdgcn_s_waitcnt(0);
    __syncthreads();
    if (tid < 4)
        __hip_atomic_fetch_add(&cnt[bx * 4 + tid], 1,
                               __ATOMIC_RELAXED, __HIP_MEMORY_SCOPE_AGENT);
}

// ---------------------------------------------------------------------------
// consumer GEMM tile: 8 waves x 64x64, 512 rows per block, A via normal loads
// (first touch after the done-counter gate). OUTMODE 0: bf16 row-major [N]
// via AGENT-scope stores (read by etype/attn blocks inside this kernel);
// OUTMODE 1: O_vertex float4 at [(b*1024+col)*32 + t] (host-read, plain).
// ---------------------------------------------------------------------------
template<int OUTMODE, int K>
__device__ __forceinline__ void consume_gemm(
    const bf16_t* __restrict__ A, const bf16_t* __restrict__ W,
    const float* __restrict__ bias, void* __restrict__ Cv,
    int N, int bx, int nbase)
{
    constexpr int K32 = K / 32;
    const int tid = threadIdx.x, lane = tid & 63, wv = tid >> 6;
    const int r16 = lane & 15, quad = lane >> 4, koff = quad * 8;
    const int mbase = bx * 512 + wv * 64;

    const bf16_t* ap[4];
#pragma unroll
    for (int i = 0; i < 4; ++i)
        ap[i] = A + (size_t)(mbase + i * 16 + r16) * K + koff;
    const bf16_t* bp[4];
#pragma unroll
    for (int j = 0; j < 4; ++j)
        bp[j] = W + (size_t)(nbase + j * 16 + r16) * K + koff;

    f32x4 acc[4][4];
#pragma unroll
    for (int i = 0; i < 4; ++i)
#pragma unroll
        for (int j = 0; j < 4; ++j) acc[i][j] = (f32x4){0.f, 0.f, 0.f, 0.f};

    for (int kc = 0; kc < K32; ++kc) {
        bf16x8 a[4], b[4];
#pragma unroll
        for (int i = 0; i < 4; ++i) a[i] = *(const bf16x8*)(ap[i] + kc * 32);
#pragma unroll
        for (int j = 0; j < 4; ++j) b[j] = *(const bf16x8*)(bp[j] + kc * 32);
#pragma unroll
        for (int i = 0; i < 4; ++i)
#pragma unroll
            for (int j = 0; j < 4; ++j)
                acc[i][j] = __builtin_amdgcn_mfma_f32_16x16x32_bf16(a[i], b[j], acc[i][j], 0, 0, 0);
    }

#pragma unroll
    for (int j = 0; j < 4; ++j) {
        int col = nbase + j * 16 + r16;
        float bf = bias[col];
#pragma unroll
        for (int i = 0; i < 4; ++i) {
            int rowq = mbase + i * 16 + quad * 4;
            if (OUTMODE == 1) {
                int b = rowq >> 5, t0 = rowq & 31;
                float4 v4;
                v4.x = acc[i][j][0] + bf; v4.y = acc[i][j][1] + bf;
                v4.z = acc[i][j][2] + bf; v4.w = acc[i][j][3] + bf;
                *(float4*)((float*)Cv + ((size_t)(b * 1024) + col) * 32 + t0) = v4;
            } else {
                bf16_t* C = (bf16_t*)Cv;
#pragma unroll
                for (int q = 0; q < 4; ++q) {
                    bf16_t hb = (bf16_t)(acc[i][j][q] + bf);
                    __hip_atomic_store(
                        (unsigned short*)(C + (size_t)(rowq + q) * N + col),
                        __builtin_bit_cast(unsigned short, hb),
                        __ATOMIC_RELAXED, __HIP_MEMORY_SCOPE_AGENT);
                }
            }
        }
    }
}

// single-poller gate: tid0 spins (sleepy), everyone else waits at the barrier.
__device__ __forceinline__ void gate_on(int* p, int thresh) {
    if (threadIdx.x == 0) {
        while (__hip_atomic_load(p, __ATOMIC_RELAXED,
                                 __HIP_MEMORY_SCOPE_AGENT) < thresh)
            __builtin_amdgcn_s_sleep(8);
    }
    __syncthreads();
    asm volatile("" ::: "memory");
}

// ---------------------------------------------------------------------------
// Fused pipeline kernel: 1136 blocks x 512 threads, 84KB LDS -> 1 block/CU.
//   conversion phase: bids 0..255 convert weights fp32->bf16 (15 chunks each)
//   0..127    gru (R5 core + gi gate)         [gate prepdone]
//   128..511  giE producers (low-t-first)     [gate prepdone]
//   512..703  giV producers (low-t-first)     [gate prepdone]
//   704..831  OV consumers (gate vdone==64)
//   832..847  vrep consumers (gate vdone==64; signal vrepdone)
//   848..879  erep consumers (gate edone==64; signal erepdone)
//   880..1007 etype (gate erepdone==32)
//   1008..1135 attn, one block per b (gate erepdone==32 && vrepdone==16)
// ---------------------------------------------------------------------------
__global__ __launch_bounds__(512) void fused_scan(
    bf16_t* __restrict__ giV, bf16_t* __restrict__ giE,
    const bf16_t* __restrict__ WhV, const bf16_t* __restrict__ WhE,
    const float* __restrict__ bhV, const float* __restrict__ bhE,
    bf16_t* __restrict__ hV, bf16_t* __restrict__ hE,
    bf16_t* __restrict__ hbuf, int* __restrict__ flags, int* __restrict__ gicnt,
    const int* __restrict__ ivtx, const int* __restrict__ iedg,
    const bf16_t* __restrict__ vemb, const bf16_t* __restrict__ eemb,
    const bf16_t* __restrict__ vwi, const bf16_t* __restrict__ ewi,
    const float* __restrict__ vbi, const float* __restrict__ ebi,
    const bf16_t* __restrict__ voutw, const float* __restrict__ voutb,
    const bf16_t* __restrict__ vrepw, const float* __restrict__ vrepb,
    const bf16_t* __restrict__ erepw, const float* __restrict__ erepb,
    bf16_t* __restrict__ vrep, bf16_t* __restrict__ erep,
    const float* __restrict__ etypeW, const float* __restrict__ etypeB,
    const float* __restrict__ src_w, const float* __restrict__ src_b,
    const float* __restrict__ dst_w, const float* __restrict__ dst_b,
    const float* __restrict__ f_vemb, const float* __restrict__ f_eemb,
    const float* __restrict__ f_vwi,  const float* __restrict__ f_ewi,
    const float* __restrict__ f_vwh,  const float* __restrict__ f_ewh,
    const float* __restrict__ f_voutw, const float* __restrict__ f_vrepw,
    const float* __restrict__ f_erepw, bf16_t* __restrict__ cvt,
    float* __restrict__ out)
{
    // ONE LDS object, 83968 B (DCE-proof): gru carves hbf+red; attn carves
    // es/vs/swf/dwf. 83968 B/block -> 1 block/CU.
    __shared__ __align__(16) char lds_all[83968];
    bf16_t (*hbf)[520] = (bf16_t (*)[520])lds_all;             // [32][520] bf16
    f32x4 (*red)[3][64] = (f32x4 (*)[3][64])(lds_all + 33280); // [4][3][64] f32x4

    const int bid = blockIdx.x;

    // ---- conversion phase: bids 0..255 (the initially-resident set) ----
    // 3592 chunks of 1024 fp32 elems; 15 chunks/block; float2 -> 2xbf16
    // agent stores; then drain -> barrier -> prepdone++ (gicnt[100]).
    if (bid < 256) {
        const int tid = threadIdx.x;
        for (int k = 0; k < 15; ++k) {
            int blk = bid * 15 + k;
            if (blk >= 3592) break;
            const float* src; bf16_t* dst; int lb;
            if (blk < 256)       { src = f_vemb;  dst = cvt + CVT_VEMB;  lb = blk; }
            else if (blk < 264)  { src = f_eemb;  dst = cvt + CVT_EEMB;  lb = blk - 256; }
            else if (blk < 648)  { src = f_vwi;   dst = cvt + CVT_VWI;   lb = blk - 264; }
            else if (blk < 1416) { src = f_ewi;   dst = cvt + CVT_EWI;   lb = blk - 648; }
            else if (blk < 2184) { src = f_vwh;   dst = cvt + CVT_VWH;   lb = blk - 1416; }
            else if (blk < 2952) { src = f_ewh;   dst = cvt + CVT_EWH;   lb = blk - 2184; }
            else if (blk < 3464) { src = f_voutw; dst = cvt + CVT_VOUT;  lb = blk - 2952; }
            else if (blk < 3528) { src = f_vrepw; dst = cvt + CVT_VREPW; lb = blk - 3464; }
            else                 { src = f_erepw; dst = cvt + CVT_EREPW; lb = blk - 3528; }
            int idx = lb * 1024 + tid * 2;
            float2 v = *(const float2*)(src + idx);
            unsigned int pk =
                (unsigned int)__builtin_bit_cast(unsigned short, (bf16_t)v.x) |
                ((unsigned int)__builtin_bit_cast(unsigned short, (bf16_t)v.y) << 16);
            __hip_atomic_store((unsigned int*)(dst + idx), pk,
                               __ATOMIC_RELAXED, __HIP_MEMORY_SCOPE_AGENT);
        }
        __builtin_amdgcn_s_waitcnt(0);
        __syncthreads();
        if (tid == 0)
            __hip_atomic_fetch_add(&gicnt[100], 1,
                                   __ATOMIC_RELAXED, __HIP_MEMORY_SCOPE_AGENT);
    }
    // gru + producers read cvt: gate on conversion complete (first-touch after)
    if (bid < 704)
        gate_on(&gicnt[100], 256);

    if (bid >= 128) {
        const int tid = threadIdx.x;
        if (bid < 512) {            // giE producers (384), low-t-first
            int g3 = bid - 128;
            int bx = g3 / 24, nb = g3 - bx * 24;
            produce_gi<2, 512>(ewi, ebi, giE, iedg, eemb, gicnt + 32, bx, nb * 64);
        } else if (bid < 704) {     // giV producers (192), low-t-first
            int g2 = bid - 512;
            int bx = g2 / 24, nb = g2 - bx * 24;
            produce_gi<1, 256>(vwi, vbi, giV, ivtx, vemb, gicnt, bx, nb * 64);
        } else if (bid < 832) {     // OV (128): gate vdone==64
            gate_on(&gicnt[96], 64);
            int cb = bid - 704;
            consume_gemm<1, 512>(hV, voutw, voutb, out, 1024, cb & 7, (cb >> 3) * 64);
        } else if (bid < 848) {     // vrep (16): gate vdone==64, signal vrepdone
            gate_on(&gicnt[96], 64);
            int cb = bid - 832;
            consume_gemm<0, 512>(hV, vrepw, vrepb, vrep, 128, cb & 7, (cb >> 3) * 64);
            __builtin_amdgcn_s_waitcnt(0);
            __syncthreads();
            if (tid == 0)
                __hip_atomic_fetch_add(&gicnt[98], 1,
                                       __ATOMIC_RELAXED, __HIP_MEMORY_SCOPE_AGENT);
        } else if (bid < 880) {     // erep (32): gate edone==64, signal erepdone
            gate_on(&gicnt[97], 64);
            int cb = bid - 848;
            consume_gemm<0, 512>(hE, erepw, erepb, erep, 128, cb & 15, (cb >> 4) * 64);
            __builtin_amdgcn_s_waitcnt(0);
            __syncthreads();
            if (tid == 0)
                __hip_atomic_fetch_add(&gicnt[99], 1,
                                       __ATOMIC_RELAXED, __HIP_MEMORY_SCOPE_AGENT);
        } else if (bid < 1008) {    // etype (128): gate erepdone==32
            gate_on(&gicnt[99], 32);
            int o = (bid - 880) * 512 + tid;     // 65536 outputs
            int te = o & 63, k = (o >> 6) & 7, b = o >> 9;
            float sacc = etypeB[k];
            const bf16_t* e = erep + ((size_t)(b * 64 + te)) * 128;
            const float* wk = etypeW + k * 128;
#pragma unroll 8
            for (int r = 0; r < 128; ++r) sacc += (float)e[r] * wk[r];
            out[OUT_OT + o] = sacc;
        } else {                    // attn (128, one per b): gate erep+vrep done
            gate_on(&gicnt[99], 32);
            gate_on(&gicnt[98], 16);
            float (*es)[129] = (float (*)[129])lds_all;              // 64 rows
            float (*vs)[129] = (float (*)[129])(lds_all + 33024);    // 32 rows
            float* swf = (float*)(lds_all + 49536);
            float* dwf = (float*)(lds_all + 50048);
            int b = bid - 1008;
            for (int f = tid; f < 64 * 128; f += 512) {
                int i = f >> 7, r = f & 127;
                es[i][r] = (float)erep[((size_t)(b * 64 + i)) * 128 + r];
            }
            for (int f = tid; f < 32 * 128; f += 512) {
                int i = f >> 7, r = f & 127;
                vs[i][r] = (float)vrep[((size_t)(b * 32 + i)) * 128 + r];
            }
            if (tid < 128) { swf[tid] = src_w[tid]; dwf[tid] = dst_w[tid]; }
            __syncthreads();
            float sb = src_b[0], db = dst_b[0];
            for (int p = tid; p < 2048; p += 512) {
                int te = p & 63, tv = p >> 6;
                float sacc = 0.f, dacc = 0.f;
#pragma unroll 4
                for (int r = 0; r < 128; ++r) {
                    float u = ftanh(es[te][r] + vs[tv][r]);
                    sacc += u * swf[r];
                    dacc += u * dwf[r];
                }
                size_t base = OUT_OE + ((size_t)(b * 32 + tv) * 2) * 64;
                out[base + te]      = sacc + sb;
                out[base + 64 + te] = dacc + db;
            }
        }
        return;
    }

    // ---- GRU core (R5 geometry, 228us solo): blocks 0..127 ----
    const int role = bid >> 6;           // 0 vertex (64 blocks), 1 edge (64)
    const int lb   = bid & 63;
    const int g    = lb & 7;             // batch group: rows g*16 .. g*16+15
    const int s    = lb >> 3;            // col-slice 0..7 (64 cols each)
    const bf16_t* gi = role ? giE : giV;
    const bf16_t* Wh = role ? WhE : WhV;
    const float*  bh = role ? bhE : bhV;
    bf16_t* hout = role ? hE : hV;
    const int T = role ? 64 : 32;
    const int slot = role * 8 + g;
    bf16_t* buf0 = hbuf + (size_t)slot * 16384;   // [2 parity][16 rows][512]
    int* fl = flags + slot * 8;                   // 8 slice flags per slot
    int* gc = role ? (gicnt + 32) : gicnt;
    int* done = role ? &gicnt[97] : &gicnt[96];
    const int bb = g * 16;

    const int tid = threadIdx.x, lane = tid & 63, w = tid >> 6;
    const int team = w >> 1, half = w & 1;        // team 0..3 (16-col strip), K-half 0..1
    const int r16 = lane & 15, quad = lane >> 4, koff = quad * 8;
    const int j = s * 64 + team * 16 + r16;       // this lane's h column (0..511)
    const int kbase = half * 256;                 // this wave's K-half

    // Wh K-half slice: 3 x 8 x bf16x8 = 96 regs requested; allocator remats
    // -> ~192KB/step L1 stream, 1.28us/step. Accepted: cheapest Wh transport
    // measured (R5 228 vs R7-LDS 309 vs R3-full 319).
    bf16x8 wfrag[3][8];
#pragma unroll
    for (int gate = 0; gate < 3; ++gate) {
        const bf16_t* wrow = Wh + ((size_t)(gate * 512 + j)) * 512 + kbase + koff;
#pragma unroll
        for (int kc = 0; kc < 8; ++kc)
            wfrag[gate][kc] = *(const bf16x8*)(wrow + kc * 32);
    }
    const float bhr = bh[j], bhz = bh[512 + j], bhn = bh[1024 + j];
    float hq[4] = {0.f, 0.f, 0.f, 0.f};           // live in half-0 waves

    for (int u = tid; u < 16 * 520; u += 512)
        ((bf16_t*)hbf)[u] = (bf16_t)0.f;          // h(0) = 0 (16 rows used)
    __syncthreads();

    for (int t = 0; t < T; ++t) {
        // ---- gi gate: wave0 polls gc[t] (sleepy), others wait at B1 ----
        if (w == 0) {
            while (__hip_atomic_load(&gc[t], __ATOMIC_RELAXED,
                                     __HIP_MEMORY_SCOPE_AGENT) < 24)
                __builtin_amdgcn_s_sleep(2);
        }
        __syncthreads();                          // B1: gi[t] visible
        asm volatile("" ::: "memory");

        // gi[t] loads (half0 only), issued before the flag wait to hide latency
        float gv[3][4];
        if (half == 0) {
#pragma unroll
            for (int gg = 0; gg < 3; ++gg)
#pragma unroll
                for (int q = 0; q < 4; ++q)
                    gv[gg][q] = (float)gi[((size_t)(t * 128 + bb + quad * 4 + q)) * 1536
                                          + gg * 512 + j];
        }

        if (t > 0) {
            // h(t) handoff: wave1 polls the 8 slice flags tight (critical path)
            if (w == 1) {
                while (!__all((int)(__hip_atomic_load(&fl[lane & 7], __ATOMIC_RELAXED,
                                                      __HIP_MEMORY_SCOPE_AGENT) >= t))) { }
            }
            __syncthreads();                      // B2: flags observed
            asm volatile("" ::: "memory");
            // full 16x512 h(t) from slot buffer -> LDS (4 x 8B per thread)
            ull_t* src = (ull_t*)(buf0 + (size_t)(t & 1) * 8192);
#pragma unroll
            for (int k = 0; k < 4; ++k) {
                int u = tid + k * 512;            // 2048 units: row = u>>7, 8B unit = u&127
                ull_t vv = __hip_atomic_load(src + u, __ATOMIC_RELAXED,
                                             __HIP_MEMORY_SCOPE_AGENT);
                *(ull_t*)&hbf[u >> 7][(u & 127) * 4] = vv;
            }
        }
        __syncthreads();                          // B3: h(t) complete in LDS

        // MFMA: partial gh over this wave's K-half; A from hbf, B from wfrag
        f32x4 ar = {0.f,0.f,0.f,0.f}, az = {0.f,0.f,0.f,0.f}, an = {0.f,0.f,0.f,0.f};
#pragma unroll
        for (int kc = 0; kc < 8; ++kc) {
            bf16x8 a = *(const bf16x8*)&hbf[r16][kbase + kc * 32 + koff];
            ar = __builtin_amdgcn_mfma_f32_16x16x32_bf16(a, wfrag[0][kc], ar, 0, 0, 0);
            az = __builtin_amdgcn_mfma_f32_16x16x32_bf16(a, wfrag[1][kc], az, 0, 0, 0);
            an = __builtin_amdgcn_mfma_f32_16x16x32_bf16(a, wfrag[2][kc], an, 0, 0, 0);
        }

        // K-half reduce: half1 publishes partials, half0 sums
        if (half == 1) {
            red[team][0][lane] = ar;
            red[team][1][lane] = az;
            red[team][2][lane] = an;
        }
        __syncthreads();                          // B4: partials ready

        bf16_t hb4[4];
        if (half == 0) {
            ar += red[team][0][lane];
            az += red[team][1][lane];
            an += red[team][2][lane];
#pragma unroll
            for (int q = 0; q < 4; ++q) {
                float r = fsigmoid(gv[0][q] + ar[q] + bhr);
                float z = fsigmoid(gv[1][q] + az[q] + bhz);
                float n = ftanh(gv[2][q] + r * (an[q] + bhn));
                float hnew = (1.0f - z) * n + z * hq[q];
                hq[q] = hnew;
                hb4[q] = (bf16_t)hnew;
            }
            if (t + 1 < T) {
                bf16_t* dstg = buf0 + (size_t)((t + 1) & 1) * 8192;
#pragma unroll
                for (int q = 0; q < 4; ++q)
                    __hip_atomic_store(
                        (unsigned short*)(dstg + (quad * 4 + q) * 512 + j),
                        __builtin_bit_cast(unsigned short, hb4[q]),
                        __ATOMIC_RELAXED, __HIP_MEMORY_SCOPE_AGENT);
            }
        }

        if (t + 1 < T) {
            __builtin_amdgcn_s_waitcnt(0);        // drain release stores
            __syncthreads();                      // B5: all drains done
            if (tid == 0)
                __hip_atomic_store(&fl[s], t + 1,
                                   __ATOMIC_RELAXED, __HIP_MEMORY_SCOPE_AGENT);
        } else {
            __syncthreads();
        }
        // hout: agent-scope stores (consumers read within this kernel)
        if (half == 0) {
#pragma unroll
            for (int q = 0; q < 4; ++q)
                __hip_atomic_store(
                    (unsigned short*)(hout + ((size_t)((bb + quad * 4 + q) * T + t)) * 512 + j),
                    __builtin_bit_cast(unsigned short, hb4[q]),
                    __ATOMIC_RELAXED, __HIP_MEMORY_SCOPE_AGENT);
        }
    }

    // signal scan completion (per role; 64 blocks each)
    __builtin_amdgcn_s_waitcnt(0);
    __syncthreads();
    if (tid == 0)
        __hip_atomic_fetch_add(done, 1, __ATOMIC_RELAXED, __HIP_MEMORY_SCOPE_AGENT);
}

extern "C" void kernel_launch(void* const* d_in, const int* in_sizes, int n_in,
                              void* d_out, int out_size, void* d_ws, size_t ws_size,
                              hipStream_t stream)
{
    const int*   input_vertex = (const int*)d_in[0];
    const int*   input_edge   = (const int*)d_in[1];
    const float* vertex_emb   = (const float*)d_in[2];
    const float* v_Wi  = (const float*)d_in[3];
    const float* v_Wh  = (const float*)d_in[4];
    const float* v_bi  = (const float*)d_in[5];
    const float* v_bh  = (const float*)d_in[6];
    const float* vout_W = (const float*)d_in[7];
    const float* vout_b = (const float*)d_in[8];
    const float* vrep_W = (const float*)d_in[9];
    const float* vrep_b = (const float*)d_in[10];
    const float* edge_emb = (const float*)d_in[11];
    const float* e_Wi  = (const float*)d_in[12];
    const float* e_Wh  = (const float*)d_in[13];
    const float* e_bi  = (const float*)d_in[14];
    const float* e_bh  = (const float*)d_in[15];
    const float* erep_W = (const float*)d_in[16];
    const float* erep_b = (const float*)d_in[17];
    const float* etype_W = (const float*)d_in[18];
    const float* etype_b = (const float*)d_in[19];
    const float* src_w = (const float*)d_in[20];
    const float* src_b = (const float*)d_in[21];
    const float* dst_w = (const float*)d_in[22];
    const float* dst_b = (const float*)d_in[23];

    bf16_t* ws   = (bf16_t*)d_ws;
    bf16_t* giV  = ws + OFF_GIV;
    bf16_t* giE  = ws + OFF_GIE;
    bf16_t* hV   = ws + OFF_HV;
    bf16_t* hE   = ws + OFF_HE;
    bf16_t* vrep = ws + OFF_VREP;
    bf16_t* erep = ws + OFF_EREP;
    bf16_t* hbuf = ws + OFF_HBUF;
    bf16_t* cvt  = ws + OFF_CVT;
    int*    flags = (int*)((char*)d_ws + FLAG_BYTE_OFF);
    int*    gicnt = (int*)((char*)d_ws + GICNT_BYTE_OFF);
    float*  out  = (float*)d_out;

    // zero flags (512B) + gicnt (512B) -- replaces prep's counter reset;
    // capture-safe (the harness reset itself enqueues hipMemsetAsync).
    hipMemsetAsync((char*)d_ws + FLAG_BYTE_OFF, 0, 1024, stream);

    // single fused pipeline: conversion + scans + producers + consumers +
    // etype + attn
    fused_scan<<<1136, 512, 0, stream>>>(
        giV, giE, cvt + CVT_VWH, cvt + CVT_EWH, v_bh, e_bh, hV, hE,
        hbuf, flags, gicnt, input_vertex, input_edge,
        cvt + CVT_VEMB, cvt + CVT_EEMB, cvt + CVT_VWI, cvt + CVT_EWI,
        v_bi, e_bi,
        cvt + CVT_VOUT, vout_b, cvt + CVT_VREPW, vrep_b,
        cvt + CVT_EREPW, erep_b, vrep, erep,
        etype_W, etype_b, src_w, src_b, dst_w, dst_b,
        vertex_emb, edge_emb, v_Wi, e_Wi, v_Wh, e_Wh,
        vout_W, vrep_W, erep_W, cvt, out);
}

// Round 14
// 434.780 us; speedup vs baseline: 1.0244x; 1.0244x over previous
//
#include <hip/hip_runtime.h>
#include <hip/hip_bf16.h>

// ---------------------------------------------------------------------------
// RNN_17214228922840: GraphRNN-ish model. fp32 I/O, bf16 MFMA compute.
//   B=128, TV=32, TE=64, VOCAB=1024, EMB=256, H=512 (3H=1536), REPR=128, NET=8
// Outputs (flat, fp32): O_vertex [128,1024,32] | O_edge [128,32,2,64] | O_edge_type [128,8,64]
// h row space b-major: row = b*T + t.   gi row space t-major: row = t*128 + b.
//
// R14 = R10 restored (measured best family: R9 428.1 / R10 429.7) + counters
// zeroed via hipMemsetAsync (prep grid 3593 -> 3592).
// Fold post-mortems (R12/R13): folding etype/attn (+5 net) and prep (+10 net)
// into the fused kernel LOST time -- in-kernel serialization (+25..37us)
// exceeded the ~15us launch cost of each extra kernel. R13's single-kernel
// run measured the fixed harness overhead: total - fused = 83us with zero
// extra launches. Floor = 83 fixed + fused 300 + prep 15 + etype/attn 16 +
// gaps ~ 428 = exactly R9/R10. This restores that operating point.
// fused_scan: R5 gru core (228us solo; 96-reg wfrag, allocator remats ->
// ~1.28us/step L1 Wh stream -- cheapest transport measured vs LDS/full-reg),
// giE producers first + low-t-first, consumers gated on done-counters,
// real 84KB LDS pad -> 1 block/CU.
// Handoffs: agent-scope stores -> s_waitcnt(0) -> barrier -> counter/flag;
// memset-zeroed counters/flags each launch (replay-safe).
// ---------------------------------------------------------------------------

typedef __bf16 bf16_t;
typedef bf16_t bf16x8 __attribute__((ext_vector_type(8)));
typedef bf16_t bf16x4 __attribute__((ext_vector_type(4)));
typedef float  f32x4  __attribute__((ext_vector_type(4)));
typedef unsigned long long ull_t;

// workspace layout (bf16 element offsets)
#define OFF_GIV  0ull                    // 4096*1536 (t-major)
#define OFF_GIE  6291456ull              // 8192*1536 (t-major)
#define OFF_HV   18874368ull             // 128*32*512 (b-major)
#define OFF_HE   20971520ull             // 128*64*512 (b-major)
#define OFF_VREP 25165824ull             // 128*32*128
#define OFF_EREP 25690112ull             // 128*64*128
#define OFF_HBUF 26738688ull             // 16 slots * 2 parity * 8192 = 262144 elems
#define FLAG_BYTE_OFF  54001664ull       // 16 slots * 8 ints = 512 B (memset-zeroed)
#define GICNT_BYTE_OFF 54002176ull       // 128 ints (memset-zeroed): [0..31] giV,
                                         // [32..95] giE, [96]=vdone, [97]=edone
#define OFF_CVT  27002880ull             // converted bf16 weights below
#define CVT_VEMB  0ull
#define CVT_EEMB  262144ull
#define CVT_VWI   270336ull
#define CVT_EWI   663552ull
#define CVT_VWH   1449984ull
#define CVT_EWH   2236416ull
#define CVT_VOUT  3022848ull
#define CVT_VREPW 3547136ull
#define CVT_EREPW 3612672ull

// output flat offsets (fp32 elements)
#define OUT_OV 0ull
#define OUT_OE 4194304ull
#define OUT_OT 4718592ull

__device__ __forceinline__ float fsigmoid(float x) {
    float e = __builtin_amdgcn_exp2f(-x * 1.4426950408889634f);
    return __builtin_amdgcn_rcpf(1.0f + e);
}
__device__ __forceinline__ float ftanh(float x) {
    x = fminf(x, 15.0f);
    float e = __builtin_amdgcn_exp2f(x * 2.8853900817779268f); // exp(2x)
    return (e - 1.0f) * __builtin_amdgcn_rcpf(e + 1.0f);
}

// ---------------------------------------------------------------------------
// prep: fp32 -> bf16 downcast of weights/embeddings (3592 blocks x 1024 elem)
// ---------------------------------------------------------------------------
__global__ __launch_bounds__(256) void prep_kernel(
    const float* __restrict__ vemb, const float* __restrict__ eemb,
    const float* __restrict__ vwi,  const float* __restrict__ ewi,
    const float* __restrict__ vwh,  const float* __restrict__ ewh,
    const float* __restrict__ voutw, const float* __restrict__ vrepw,
    const float* __restrict__ erepw, bf16_t* __restrict__ cvt)
{
    int blk = blockIdx.x;
    const float* src; bf16_t* dst; int lb;
    if (blk < 256)       { src = vemb;  dst = cvt + CVT_VEMB;  lb = blk; }
    else if (blk < 264)  { src = eemb;  dst = cvt + CVT_EEMB;  lb = blk - 256; }
    else if (blk < 648)  { src = vwi;   dst = cvt + CVT_VWI;   lb = blk - 264; }
    else if (blk < 1416) { src = ewi;   dst = cvt + CVT_EWI;   lb = blk - 648; }
    else if (blk < 2184) { src = vwh;   dst = cvt + CVT_VWH;   lb = blk - 1416; }
    else if (blk < 2952) { src = ewh;   dst = cvt + CVT_EWH;   lb = blk - 2184; }
    else if (blk < 3464) { src = voutw; dst = cvt + CVT_VOUT;  lb = blk - 2952; }
    else if (blk < 3528) { src = vrepw; dst = cvt + CVT_VREPW; lb = blk - 3464; }
    else                 { src = erepw; dst = cvt + CVT_EREPW; lb = blk - 3528; }
    int idx = lb * 1024 + threadIdx.x * 4;
    float4 v = *(const float4*)(src + idx);
    bf16x4 o;
    o[0] = (bf16_t)v.x; o[1] = (bf16_t)v.y; o[2] = (bf16_t)v.z; o[3] = (bf16_t)v.w;
    *(bf16x4*)(dst + idx) = o;
}

// ---------------------------------------------------------------------------
// gi producer tile: 8 waves x 64x64, rows t-major (row = t*128 + b). Agent
// stores -> waitcnt -> barrier -> 4 slice-counter adds (R3-validated).
// ---------------------------------------------------------------------------
template<int GATHER, int K>
__device__ __forceinline__ void produce_gi(
    const bf16_t* __restrict__ W, const float* __restrict__ bias,
    bf16_t* __restrict__ C, const int* __restrict__ gidx,
    const bf16_t* __restrict__ emb, int* __restrict__ cnt, int bx, int nbase)
{
    constexpr int K32 = K / 32;
    const int tid = threadIdx.x, lane = tid & 63, wv = tid >> 6;
    const int r16 = lane & 15, quad = lane >> 4, koff = quad * 8;
    const int mbase = bx * 512 + wv * 64;

    const bf16_t* ap0[4];
    const bf16_t* ap1[4];
#pragma unroll
    for (int i = 0; i < 4; ++i) {
        int row = mbase + i * 16 + r16;
        int b = row & 127, t = row >> 7;
        if (GATHER == 1) {
            ap0[i] = emb + (size_t)gidx[b * 32 + t] * 256 + koff;
            ap1[i] = ap0[i];
        } else {
            int c = (b * 64 + t) * 3;
            ap0[i] = emb + (size_t)gidx[c] * 256 + koff;
            ap1[i] = emb + (size_t)gidx[c + 1] * 256 + koff;
        }
    }
    const bf16_t* bp[4];
#pragma unroll
    for (int j = 0; j < 4; ++j)
        bp[j] = W + (size_t)(nbase + j * 16 + r16) * K + koff;

    f32x4 acc[4][4];
#pragma unroll
    for (int i = 0; i < 4; ++i)
#pragma unroll
        for (int j = 0; j < 4; ++j) acc[i][j] = (f32x4){0.f, 0.f, 0.f, 0.f};

    for (int kc = 0; kc < K32; ++kc) {
        bf16x8 a[4], b[4];
#pragma unroll
        for (int i = 0; i < 4; ++i) {
            const bf16_t* p;
            if (GATHER == 2) p = (kc < 8) ? (ap0[i] + kc * 32) : (ap1[i] + (kc - 8) * 32);
            else             p = ap0[i] + kc * 32;
            a[i] = *(const bf16x8*)p;
        }
#pragma unroll
        for (int j = 0; j < 4; ++j) b[j] = *(const bf16x8*)(bp[j] + kc * 32);
#pragma unroll
        for (int i = 0; i < 4; ++i)
#pragma unroll
            for (int j = 0; j < 4; ++j)
                acc[i][j] = __builtin_amdgcn_mfma_f32_16x16x32_bf16(a[i], b[j], acc[i][j], 0, 0, 0);
    }

#pragma unroll
    for (int j = 0; j < 4; ++j) {
        int col = nbase + j * 16 + r16;
        float bf = bias[col];
#pragma unroll
        for (int i = 0; i < 4; ++i) {
#pragma unroll
            for (int q = 0; q < 4; ++q) {
                int row = mbase + i * 16 + quad * 4 + q;
                bf16_t hb = (bf16_t)(acc[i][j][q] + bf);
                __hip_atomic_store((unsigned short*)(C + (size_t)row * 1536 + col),
                                   __builtin_bit_cast(unsigned short, hb),
                                   __ATOMIC_RELAXED, __HIP_MEMORY_SCOPE_AGENT);
            }
        }
    }
    __builtin_amdgcn_s_waitcnt(0);
    __syncthreads();
    if (tid < 4)
        __hip_atomic_fetch_add(&cnt[bx * 4 + tid], 1,
                               __ATOMIC_RELAXED, __HIP_MEMORY_SCOPE_AGENT);
}

// ---------------------------------------------------------------------------
// consumer GEMM tile: 8 waves x 64x64, 512 rows per block, A via normal loads
// (first touch after the done-counter gate). OUTMODE 0: bf16 row-major [N];
// OUTMODE 1: O_vertex float4 at [(b*1024+col)*32 + t].
// ---------------------------------------------------------------------------
template<int OUTMODE, int K>
__device__ __forceinline__ void consume_gemm(
    const bf16_t* __restrict__ A, const bf16_t* __restrict__ W,
    const float* __restrict__ bias, void* __restrict__ Cv,
    int N, int bx, int nbase)
{
    constexpr int K32 = K / 32;
    const int tid = threadIdx.x, lane = tid & 63, wv = tid >> 6;
    const int r16 = lane & 15, quad = lane >> 4, koff = quad * 8;
    const int mbase = bx * 512 + wv * 64;

    const bf16_t* ap[4];
#pragma unroll
    for (int i = 0; i < 4; ++i)
        ap[i] = A + (size_t)(mbase + i * 16 + r16) * K + koff;
    const bf16_t* bp[4];
#pragma unroll
    for (int j = 0; j < 4; ++j)
        bp[j] = W + (size_t)(nbase + j * 16 + r16) * K + koff;

    f32x4 acc[4][4];
#pragma unroll
    for (int i = 0; i < 4; ++i)
#pragma unroll
        for (int j = 0; j < 4; ++j) acc[i][j] = (f32x4){0.f, 0.f, 0.f, 0.f};

    for (int kc = 0; kc < K32; ++kc) {
        bf16x8 a[4], b[4];
#pragma unroll
        for (int i = 0; i < 4; ++i) a[i] = *(const bf16x8*)(ap[i] + kc * 32);
#pragma unroll
        for (int j = 0; j < 4; ++j) b[j] = *(const bf16x8*)(bp[j] + kc * 32);
#pragma unroll
        for (int i = 0; i < 4; ++i)
#pragma unroll
            for (int j = 0; j < 4; ++j)
                acc[i][j] = __builtin_amdgcn_mfma_f32_16x16x32_bf16(a[i], b[j], acc[i][j], 0, 0, 0);
    }

#pragma unroll
    for (int j = 0; j < 4; ++j) {
        int col = nbase + j * 16 + r16;
        float bf = bias[col];
#pragma unroll
        for (int i = 0; i < 4; ++i) {
            int rowq = mbase + i * 16 + quad * 4;
            if (OUTMODE == 1) {
                int b = rowq >> 5, t0 = rowq & 31;
                float4 v4;
                v4.x = acc[i][j][0] + bf; v4.y = acc[i][j][1] + bf;
                v4.z = acc[i][j][2] + bf; v4.w = acc[i][j][3] + bf;
                *(float4*)((float*)Cv + ((size_t)(b * 1024) + col) * 32 + t0) = v4;
            } else {
                bf16_t* C = (bf16_t*)Cv;
#pragma unroll
                for (int q = 0; q < 4; ++q)
                    C[(size_t)(rowq + q) * N + col] = (bf16_t)(acc[i][j][q] + bf);
            }
        }
    }
}

// single-poller gate: tid0 spins (sleepy), everyone else waits at the barrier.
__device__ __forceinline__ void gate_on(int* p, int thresh) {
    if (threadIdx.x == 0) {
        while (__hip_atomic_load(p, __ATOMIC_RELAXED,
                                 __HIP_MEMORY_SCOPE_AGENT) < thresh)
            __builtin_amdgcn_s_sleep(8);
    }
    __syncthreads();
    asm volatile("" ::: "memory");
}

// ---------------------------------------------------------------------------
// Fused pipeline kernel: 880 blocks x 512 threads, 84KB LDS (real) -> 1/CU.
//   0..127   gru (R5 core + gi gate)
//   128..511 giE producers (low-t-first)
//   512..703 giV producers (low-t-first)
//   704..831 OV consumers, 832..847 vrep (gate vdone==64)
//   848..879 erep consumers (gate edone==64)
// ---------------------------------------------------------------------------
__global__ __launch_bounds__(512) void fused_scan(
    bf16_t* __restrict__ giV, bf16_t* __restrict__ giE,
    const bf16_t* __restrict__ WhV, const bf16_t* __restrict__ WhE,
    const float* __restrict__ bhV, const float* __restrict__ bhE,
    bf16_t* __restrict__ hV, bf16_t* __restrict__ hE,
    bf16_t* __restrict__ hbuf, int* __restrict__ flags, int* __restrict__ gicnt,
    const int* __restrict__ ivtx, const int* __restrict__ iedg,
    const bf16_t* __restrict__ vemb, const bf16_t* __restrict__ eemb,
    const bf16_t* __restrict__ vwi, const bf16_t* __restrict__ ewi,
    const float* __restrict__ vbi, const float* __restrict__ ebi,
    const bf16_t* __restrict__ voutw, const float* __restrict__ voutb,
    const bf16_t* __restrict__ vrepw, const float* __restrict__ vrepb,
    const bf16_t* __restrict__ erepw, const float* __restrict__ erepb,
    bf16_t* __restrict__ vrep, bf16_t* __restrict__ erep,
    float* __restrict__ out)
{
    // ONE LDS object, 83968 B: hbf (33280) + red (12288) + pad. A single
    // accessed array is allocated whole -- DCE cannot shrink it (R9 lesson).
    // 83968 B/block -> 1 block/CU.
    __shared__ __align__(16) char lds_all[83968];
    bf16_t (*hbf)[520] = (bf16_t (*)[520])lds_all;             // [32][520] bf16
    f32x4 (*red)[3][64] = (f32x4 (*)[3][64])(lds_all + 33280); // [4][3][64] f32x4

    const int bid = blockIdx.x;

    if (bid >= 128) {
        if (bid < 512) {            // giE producers (384), low-t-first
            int g3 = bid - 128;
            int bx = g3 / 24, nb = g3 - bx * 24;
            produce_gi<2, 512>(ewi, ebi, giE, iedg, eemb, gicnt + 32, bx, nb * 64);
        } else if (bid < 704) {     // giV producers (192), low-t-first
            int g2 = bid - 512;
            int bx = g2 / 24, nb = g2 - bx * 24;
            produce_gi<1, 256>(vwi, vbi, giV, ivtx, vemb, gicnt, bx, nb * 64);
        } else if (bid < 848) {     // OV (128) + vrep (16): gate vdone==64
            gate_on(&gicnt[96], 64);
            if (bid < 832) {
                int cb = bid - 704;
                consume_gemm<1, 512>(hV, voutw, voutb, out, 1024, cb & 7, (cb >> 3) * 64);
            } else {
                int cb = bid - 832;
                consume_gemm<0, 512>(hV, vrepw, vrepb, vrep, 128, cb & 7, (cb >> 3) * 64);
            }
        } else {                    // erep consumers (32): gate edone==64
            gate_on(&gicnt[97], 64);
            int cb = bid - 848;
            consume_gemm<0, 512>(hE, erepw, erepb, erep, 128, cb & 15, (cb >> 4) * 64);
        }
        return;
    }

    // ---- GRU core (R5 geometry, 228us solo): blocks 0..127 ----
    const int role = bid >> 6;           // 0 vertex (64 blocks), 1 edge (64)
    const int lb   = bid & 63;
    const int g    = lb & 7;             // batch group: rows g*16 .. g*16+15
    const int s    = lb >> 3;            // col-slice 0..7 (64 cols each)
    const bf16_t* gi = role ? giE : giV;
    const bf16_t* Wh = role ? WhE : WhV;
    const float*  bh = role ? bhE : bhV;
    bf16_t* hout = role ? hE : hV;
    const int T = role ? 64 : 32;
    const int slot = role * 8 + g;
    bf16_t* buf0 = hbuf + (size_t)slot * 16384;   // [2 parity][16 rows][512]
    int* fl = flags + slot * 8;                   // 8 slice flags per slot
    int* gc = role ? (gicnt + 32) : gicnt;
    int* done = role ? &gicnt[97] : &gicnt[96];
    const int bb = g * 16;

    const int tid = threadIdx.x, lane = tid & 63, w = tid >> 6;
    const int team = w >> 1, half = w & 1;        // team 0..3 (16-col strip), K-half 0..1
    const int r16 = lane & 15, quad = lane >> 4, koff = quad * 8;
    const int j = s * 64 + team * 16 + r16;       // this lane's h column (0..511)
    const int kbase = half * 256;                 // this wave's K-half

    // Wh K-half slice: 3 x 8 x bf16x8 = 96 regs requested; allocator remats
    // -> ~192KB/step L1 stream, 1.28us/step. Accepted: cheapest Wh transport
    // measured (R5 228 vs R7-LDS 309 vs R3-full 319).
    bf16x8 wfrag[3][8];
#pragma unroll
    for (int gate = 0; gate < 3; ++gate) {
        const bf16_t* wrow = Wh + ((size_t)(gate * 512 + j)) * 512 + kbase + koff;
#pragma unroll
        for (int kc = 0; kc < 8; ++kc)
            wfrag[gate][kc] = *(const bf16x8*)(wrow + kc * 32);
    }
    const float bhr = bh[j], bhz = bh[512 + j], bhn = bh[1024 + j];
    float hq[4] = {0.f, 0.f, 0.f, 0.f};           // live in half-0 waves

    for (int u = tid; u < 16 * 520; u += 512)
        ((bf16_t*)hbf)[u] = (bf16_t)0.f;          // h(0) = 0 (16 rows used)
    __syncthreads();

    for (int t = 0; t < T; ++t) {
        // ---- gi gate: wave0 polls gc[t] (sleepy; passes instantly once
        //      producers are ahead), everyone else waits at B1 ----
        if (w == 0) {
            while (__hip_atomic_load(&gc[t], __ATOMIC_RELAXED,
                                     __HIP_MEMORY_SCOPE_AGENT) < 24)
                __builtin_amdgcn_s_sleep(2);
        }
        __syncthreads();                          // B1: gi[t] visible
        asm volatile("" ::: "memory");

        // gi[t] loads (half0 only), issued before the flag wait to hide latency
        float gv[3][4];
        if (half == 0) {
#pragma unroll
            for (int gg = 0; gg < 3; ++gg)
#pragma unroll
                for (int q = 0; q < 4; ++q)
                    gv[gg][q] = (float)gi[((size_t)(t * 128 + bb + quad * 4 + q)) * 1536
                                          + gg * 512 + j];
        }

        if (t > 0) {
            // h(t) handoff: wave1 polls the 8 slice flags tight (critical path)
            if (w == 1) {
                while (!__all((int)(__hip_atomic_load(&fl[lane & 7], __ATOMIC_RELAXED,
                                                      __HIP_MEMORY_SCOPE_AGENT) >= t))) { }
            }
            __syncthreads();                      // B2: flags observed
            asm volatile("" ::: "memory");
            // full 16x512 h(t) from slot buffer -> LDS (4 x 8B per thread)
            ull_t* src = (ull_t*)(buf0 + (size_t)(t & 1) * 8192);
#pragma unroll
            for (int k = 0; k < 4; ++k) {
                int u = tid + k * 512;            // 2048 units: row = u>>7, 8B unit = u&127
                ull_t vv = __hip_atomic_load(src + u, __ATOMIC_RELAXED,
                                             __HIP_MEMORY_SCOPE_AGENT);
                *(ull_t*)&hbf[u >> 7][(u & 127) * 4] = vv;
            }
        }
        __syncthreads();                          // B3: h(t) complete in LDS

        // MFMA: partial gh over this wave's K-half; A from hbf, B from wfrag
        f32x4 ar = {0.f,0.f,0.f,0.f}, az = {0.f,0.f,0.f,0.f}, an = {0.f,0.f,0.f,0.f};
#pragma unroll
        for (int kc = 0; kc < 8; ++kc) {
            bf16x8 a = *(const bf16x8*)&hbf[r16][kbase + kc * 32 + koff];
            ar = __builtin_amdgcn_mfma_f32_16x16x32_bf16(a, wfrag[0][kc], ar, 0, 0, 0);
            az = __builtin_amdgcn_mfma_f32_16x16x32_bf16(a, wfrag[1][kc], az, 0, 0, 0);
            an = __builtin_amdgcn_mfma_f32_16x16x32_bf16(a, wfrag[2][kc], an, 0, 0, 0);
        }

        // K-half reduce: half1 publishes partials, half0 sums
        if (half == 1) {
            red[team][0][lane] = ar;
            red[team][1][lane] = az;
            red[team][2][lane] = an;
        }
        __syncthreads();                          // B4: partials ready

        bf16_t hb4[4];
        if (half == 0) {
            ar += red[team][0][lane];
            az += red[team][1][lane];
            an += red[team][2][lane];
#pragma unroll
            for (int q = 0; q < 4; ++q) {
                float r = fsigmoid(gv[0][q] + ar[q] + bhr);
                float z = fsigmoid(gv[1][q] + az[q] + bhz);
                float n = ftanh(gv[2][q] + r * (an[q] + bhn));
                float hnew = (1.0f - z) * n + z * hq[q];
                hq[q] = hnew;
                hb4[q] = (bf16_t)hnew;
            }
            if (t + 1 < T) {
                bf16_t* dstg = buf0 + (size_t)((t + 1) & 1) * 8192;
#pragma unroll
                for (int q = 0; q < 4; ++q)
                    __hip_atomic_store(
                        (unsigned short*)(dstg + (quad * 4 + q) * 512 + j),
                        __builtin_bit_cast(unsigned short, hb4[q]),
                        __ATOMIC_RELAXED, __HIP_MEMORY_SCOPE_AGENT);
            }
        }

        if (t + 1 < T) {
            __builtin_amdgcn_s_waitcnt(0);        // drain release stores
            __syncthreads();                      // B5: all drains done
            if (tid == 0)
                __hip_atomic_store(&fl[s], t + 1,
                                   __ATOMIC_RELAXED, __HIP_MEMORY_SCOPE_AGENT);
        } else {
            __syncthreads();
        }
        // hout: agent-scope stores (consumers read within this kernel)
        if (half == 0) {
#pragma unroll
            for (int q = 0; q < 4; ++q)
                __hip_atomic_store(
                    (unsigned short*)(hout + ((size_t)((bb + quad * 4 + q) * T + t)) * 512 + j),
                    __builtin_bit_cast(unsigned short, hb4[q]),
                    __ATOMIC_RELAXED, __HIP_MEMORY_SCOPE_AGENT);
        }
    }

    // signal scan completion (per role; 64 blocks each)
    __builtin_amdgcn_s_waitcnt(0);
    __syncthreads();
    if (tid == 0)
        __hip_atomic_fetch_add(done, 1, __ATOMIC_RELAXED, __HIP_MEMORY_SCOPE_AGENT);
}

// O_edge_type[b,k,te] = erep[b,te,:] . etype_W[k,:] + etype_b[k]
__global__ __launch_bounds__(256) void etype_kernel(
    const bf16_t* __restrict__ erep, const float* __restrict__ W,
    const float* __restrict__ bias, float* __restrict__ out)
{
    int o = blockIdx.x * 256 + threadIdx.x;      // 65536 outputs
    int te = o & 63, k = (o >> 6) & 7, b = o >> 9;
    float sacc = bias[k];
    const bf16_t* e = erep + ((size_t)(b * 64 + te)) * 128;
    const float* w = W + k * 128;
#pragma unroll 8
    for (int r = 0; r < 128; ++r) sacc += (float)e[r] * w[r];
    out[OUT_OT + o] = sacc;
}

// O_edge[b,tv,{0,1},te] = sum_r tanh(e[b,te,r]+v[b,tv,r]) * {src,dst}_w[r] + b
__global__ __launch_bounds__(256) void attn_kernel(
    const bf16_t* __restrict__ erep, const bf16_t* __restrict__ vrep,
    const float* __restrict__ src_w, const float* __restrict__ src_b,
    const float* __restrict__ dst_w, const float* __restrict__ dst_b,
    float* __restrict__ out)
{
    int b = blockIdx.x >> 1, half = blockIdx.x & 1;
    __shared__ float es[32][129], vs[32][129], swf[128], dwf[128];
    int tid = threadIdx.x;
    for (int f = tid; f < 32 * 128; f += 256) {
        int i = f >> 7, r = f & 127;
        es[i][r] = (float)erep[((size_t)(b * 64 + half * 32 + i)) * 128 + r];
        vs[i][r] = (float)vrep[((size_t)(b * 32 + i)) * 128 + r];
    }
    if (tid < 128) { swf[tid] = src_w[tid]; dwf[tid] = dst_w[tid]; }
    __syncthreads();
    float sb = src_b[0], db = dst_b[0];
    for (int p = tid; p < 1024; p += 256) {
        int te = p & 31, tv = p >> 5;
        float sacc = 0.f, dacc = 0.f;
#pragma unroll 4
        for (int r = 0; r < 128; ++r) {
            float u = ftanh(es[te][r] + vs[tv][r]);
            sacc += u * swf[r];
            dacc += u * dwf[r];
        }
        int teg = half * 32 + te;
        size_t base = OUT_OE + ((size_t)(b * 32 + tv) * 2) * 64;
        out[base + teg]      = sacc + sb;
        out[base + 64 + teg] = dacc + db;
    }
}

extern "C" void kernel_launch(void* const* d_in, const int* in_sizes, int n_in,
                              void* d_out, int out_size, void* d_ws, size_t ws_size,
                              hipStream_t stream)
{
    const int*   input_vertex = (const int*)d_in[0];
    const int*   input_edge   = (const int*)d_in[1];
    const float* vertex_emb   = (const float*)d_in[2];
    const float* v_Wi  = (const float*)d_in[3];
    const float* v_Wh  = (const float*)d_in[4];
    const float* v_bi  = (const float*)d_in[5];
    const float* v_bh  = (const float*)d_in[6];
    const float* vout_W = (const float*)d_in[7];
    const float* vout_b = (const float*)d_in[8];
    const float* vrep_W = (const float*)d_in[9];
    const float* vrep_b = (const float*)d_in[10];
    const float* edge_emb = (const float*)d_in[11];
    const float* e_Wi  = (const float*)d_in[12];
    const float* e_Wh  = (const float*)d_in[13];
    const float* e_bi  = (const float*)d_in[14];
    const float* e_bh  = (const float*)d_in[15];
    const float* erep_W = (const float*)d_in[16];
    const float* erep_b = (const float*)d_in[17];
    const float* etype_W = (const float*)d_in[18];
    const float* etype_b = (const float*)d_in[19];
    const float* src_w = (const float*)d_in[20];
    const float* src_b = (const float*)d_in[21];
    const float* dst_w = (const float*)d_in[22];
    const float* dst_b = (const float*)d_in[23];

    bf16_t* ws   = (bf16_t*)d_ws;
    bf16_t* giV  = ws + OFF_GIV;
    bf16_t* giE  = ws + OFF_GIE;
    bf16_t* hV   = ws + OFF_HV;
    bf16_t* hE   = ws + OFF_HE;
    bf16_t* vrep = ws + OFF_VREP;
    bf16_t* erep = ws + OFF_EREP;
    bf16_t* hbuf = ws + OFF_HBUF;
    bf16_t* cvt  = ws + OFF_CVT;
    int*    flags = (int*)((char*)d_ws + FLAG_BYTE_OFF);
    int*    gicnt = (int*)((char*)d_ws + GICNT_BYTE_OFF);
    float*  out  = (float*)d_out;

    // zero flags (512B) + gicnt (512B) on-stream (capture-safe, R13-proven)
    hipMemsetAsync((char*)d_ws + FLAG_BYTE_OFF, 0, 1024, stream);

    // 1) downcast weights to bf16
    prep_kernel<<<3592, 256, 0, stream>>>(vertex_emb, edge_emb, v_Wi, e_Wi, v_Wh, e_Wh,
                                          vout_W, vrep_W, erep_W, cvt);

    // 2) fused pipeline: scans + gi producers + OV/vrep/erep consumers
    fused_scan<<<880, 512, 0, stream>>>(
        giV, giE, cvt + CVT_VWH, cvt + CVT_EWH, v_bh, e_bh, hV, hE,
        hbuf, flags, gicnt, input_vertex, input_edge,
        cvt + CVT_VEMB, cvt + CVT_EEMB, cvt + CVT_VWI, cvt + CVT_EWI,
        v_bi, e_bi,
        cvt + CVT_VOUT, vout_b, cvt + CVT_VREPW, vrep_b,
        cvt + CVT_EREPW, erep_b, vrep, erep, out);

    // 3) epilogues
    etype_kernel<<<256, 256, 0, stream>>>(erep, etype_W, etype_b, out);
    attn_kernel<<<256, 256, 0, stream>>>(erep, vrep, src_w, src_b, dst_w, dst_b, out);
}

// Round 16
// 419.379 us; speedup vs baseline: 1.0620x; 1.0367x over previous
//
#include <hip/hip_runtime.h>
#include <hip/hip_bf16.h>

// ---------------------------------------------------------------------------
// RNN_17214228922840: GraphRNN-ish model. fp32 I/O, bf16 MFMA compute.
//   B=128, TV=32, TE=64, VOCAB=1024, EMB=256, H=512 (3H=1536), REPR=128, NET=8
// Outputs (flat, fp32): O_vertex [128,1024,32] | O_edge [128,32,2,64] | O_edge_type [128,8,64]
// h row space b-major: row = b*T + t.   gi row space t-major: row = t*128 + b.
//
// R16 = R15 resubmitted verbatim. "container failed twice" matches the R2/R11
// infra signature (both ran clean on identical resubmission: R3, R12). Race
// re-audit of the sub-flag scheme found no defect: sub-flag transitivity
// guarantees every block finished reading parity (t+1)&1's old contents
// (h(t-1)) before any block overwrites it at step t; hbf is fenced by B4+B1;
// release path never waits on the polling wave (acyclic).
//
// R15 change over R14 (family best 428-435): distributed sub-flag release.
// Each half-0 wave (team) signals its OWN sub-flag right after its own
// s_waitcnt(0) -- no B5 barrier, no tid0 relay. 32 sub-flags/slot at
// flags+256 (memset region 4KB, ends exactly at cvt). Wave1 polls 32 dwords.
// B1 is the iteration join; 5 -> 4 barriers/step. Predicted fused 278-292.
// ---------------------------------------------------------------------------

typedef __bf16 bf16_t;
typedef bf16_t bf16x8 __attribute__((ext_vector_type(8)));
typedef bf16_t bf16x4 __attribute__((ext_vector_type(4)));
typedef float  f32x4  __attribute__((ext_vector_type(4)));
typedef unsigned long long ull_t;

// workspace layout (bf16 element offsets)
#define OFF_GIV  0ull                    // 4096*1536 (t-major)
#define OFF_GIE  6291456ull              // 8192*1536 (t-major)
#define OFF_HV   18874368ull             // 128*32*512 (b-major)
#define OFF_HE   20971520ull             // 128*64*512 (b-major)
#define OFF_VREP 25165824ull             // 128*32*128
#define OFF_EREP 25690112ull             // 128*64*128
#define OFF_HBUF 26738688ull             // 16 slots * 2 parity * 8192 = 262144 elems
#define FLAG_BYTE_OFF  54001664ull       // control region, memset 4096B each launch:
                                         //   +0    legacy flags (unused, 512B)
                                         //   +512  gicnt: 128 ints ([0..31] giV,
                                         //          [32..95] giE, [96]=vdone, [97]=edone)
                                         //   +1024 sub-flags: 16 slots * 32 ints (2048B)
                                         //   +3072 slack (1024B); region ends at cvt
#define GICNT_BYTE_OFF 54002176ull
#define OFF_CVT  27002880ull             // converted bf16 weights below (byte 54005760)
#define CVT_VEMB  0ull
#define CVT_EEMB  262144ull
#define CVT_VWI   270336ull
#define CVT_EWI   663552ull
#define CVT_VWH   1449984ull
#define CVT_EWH   2236416ull
#define CVT_VOUT  3022848ull
#define CVT_VREPW 3547136ull
#define CVT_EREPW 3612672ull

// output flat offsets (fp32 elements)
#define OUT_OV 0ull
#define OUT_OE 4194304ull
#define OUT_OT 4718592ull

__device__ __forceinline__ float fsigmoid(float x) {
    float e = __builtin_amdgcn_exp2f(-x * 1.4426950408889634f);
    return __builtin_amdgcn_rcpf(1.0f + e);
}
__device__ __forceinline__ float ftanh(float x) {
    x = fminf(x, 15.0f);
    float e = __builtin_amdgcn_exp2f(x * 2.8853900817779268f); // exp(2x)
    return (e - 1.0f) * __builtin_amdgcn_rcpf(e + 1.0f);
}

// ---------------------------------------------------------------------------
// prep: fp32 -> bf16 downcast of weights/embeddings (3592 blocks x 1024 elem)
// ---------------------------------------------------------------------------
__global__ __launch_bounds__(256) void prep_kernel(
    const float* __restrict__ vemb, const float* __restrict__ eemb,
    const float* __restrict__ vwi,  const float* __restrict__ ewi,
    const float* __restrict__ vwh,  const float* __restrict__ ewh,
    const float* __restrict__ voutw, const float* __restrict__ vrepw,
    const float* __restrict__ erepw, bf16_t* __restrict__ cvt)
{
    int blk = blockIdx.x;
    const float* src; bf16_t* dst; int lb;
    if (blk < 256)       { src = vemb;  dst = cvt + CVT_VEMB;  lb = blk; }
    else if (blk < 264)  { src = eemb;  dst = cvt + CVT_EEMB;  lb = blk - 256; }
    else if (blk < 648)  { src = vwi;   dst = cvt + CVT_VWI;   lb = blk - 264; }
    else if (blk < 1416) { src = ewi;   dst = cvt + CVT_EWI;   lb = blk - 648; }
    else if (blk < 2184) { src = vwh;   dst = cvt + CVT_VWH;   lb = blk - 1416; }
    else if (blk < 2952) { src = ewh;   dst = cvt + CVT_EWH;   lb = blk - 2184; }
    else if (blk < 3464) { src = voutw; dst = cvt + CVT_VOUT;  lb = blk - 2952; }
    else if (blk < 3528) { src = vrepw; dst = cvt + CVT_VREPW; lb = blk - 3464; }
    else                 { src = erepw; dst = cvt + CVT_EREPW; lb = blk - 3528; }
    int idx = lb * 1024 + threadIdx.x * 4;
    float4 v = *(const float4*)(src + idx);
    bf16x4 o;
    o[0] = (bf16_t)v.x; o[1] = (bf16_t)v.y; o[2] = (bf16_t)v.z; o[3] = (bf16_t)v.w;
    *(bf16x4*)(dst + idx) = o;
}

// ---------------------------------------------------------------------------
// gi producer tile: 8 waves x 64x64, rows t-major (row = t*128 + b). Agent
// stores -> waitcnt -> barrier -> 4 slice-counter adds (R3-validated).
// ---------------------------------------------------------------------------
template<int GATHER, int K>
__device__ __forceinline__ void produce_gi(
    const bf16_t* __restrict__ W, const float* __restrict__ bias,
    bf16_t* __restrict__ C, const int* __restrict__ gidx,
    const bf16_t* __restrict__ emb, int* __restrict__ cnt, int bx, int nbase)
{
    constexpr int K32 = K / 32;
    const int tid = threadIdx.x, lane = tid & 63, wv = tid >> 6;
    const int r16 = lane & 15, quad = lane >> 4, koff = quad * 8;
    const int mbase = bx * 512 + wv * 64;

    const bf16_t* ap0[4];
    const bf16_t* ap1[4];
#pragma unroll
    for (int i = 0; i < 4; ++i) {
        int row = mbase + i * 16 + r16;
        int b = row & 127, t = row >> 7;
        if (GATHER == 1) {
            ap0[i] = emb + (size_t)gidx[b * 32 + t] * 256 + koff;
            ap1[i] = ap0[i];
        } else {
            int c = (b * 64 + t) * 3;
            ap0[i] = emb + (size_t)gidx[c] * 256 + koff;
            ap1[i] = emb + (size_t)gidx[c + 1] * 256 + koff;
        }
    }
    const bf16_t* bp[4];
#pragma unroll
    for (int j = 0; j < 4; ++j)
        bp[j] = W + (size_t)(nbase + j * 16 + r16) * K + koff;

    f32x4 acc[4][4];
#pragma unroll
    for (int i = 0; i < 4; ++i)
#pragma unroll
        for (int j = 0; j < 4; ++j) acc[i][j] = (f32x4){0.f, 0.f, 0.f, 0.f};

    for (int kc = 0; kc < K32; ++kc) {
        bf16x8 a[4], b[4];
#pragma unroll
        for (int i = 0; i < 4; ++i) {
            const bf16_t* p;
            if (GATHER == 2) p = (kc < 8) ? (ap0[i] + kc * 32) : (ap1[i] + (kc - 8) * 32);
            else             p = ap0[i] + kc * 32;
            a[i] = *(const bf16x8*)p;
        }
#pragma unroll
        for (int j = 0; j < 4; ++j) b[j] = *(const bf16x8*)(bp[j] + kc * 32);
#pragma unroll
        for (int i = 0; i < 4; ++i)
#pragma unroll
            for (int j = 0; j < 4; ++j)
                acc[i][j] = __builtin_amdgcn_mfma_f32_16x16x32_bf16(a[i], b[j], acc[i][j], 0, 0, 0);
    }

#pragma unroll
    for (int j = 0; j < 4; ++j) {
        int col = nbase + j * 16 + r16;
        float bf = bias[col];
#pragma unroll
        for (int i = 0; i < 4; ++i) {
#pragma unroll
            for (int q = 0; q < 4; ++q) {
                int row = mbase + i * 16 + quad * 4 + q;
                bf16_t hb = (bf16_t)(acc[i][j][q] + bf);
                __hip_atomic_store((unsigned short*)(C + (size_t)row * 1536 + col),
                                   __builtin_bit_cast(unsigned short, hb),
                                   __ATOMIC_RELAXED, __HIP_MEMORY_SCOPE_AGENT);
            }
        }
    }
    __builtin_amdgcn_s_waitcnt(0);
    __syncthreads();
    if (tid < 4)
        __hip_atomic_fetch_add(&cnt[bx * 4 + tid], 1,
                               __ATOMIC_RELAXED, __HIP_MEMORY_SCOPE_AGENT);
}

// ---------------------------------------------------------------------------
// consumer GEMM tile: 8 waves x 64x64, 512 rows per block, A via normal loads
// (first touch after the done-counter gate). OUTMODE 0: bf16 row-major [N];
// OUTMODE 1: O_vertex float4 at [(b*1024+col)*32 + t].
// ---------------------------------------------------------------------------
template<int OUTMODE, int K>
__device__ __forceinline__ void consume_gemm(
    const bf16_t* __restrict__ A, const bf16_t* __restrict__ W,
    const float* __restrict__ bias, void* __restrict__ Cv,
    int N, int bx, int nbase)
{
    constexpr int K32 = K / 32;
    const int tid = threadIdx.x, lane = tid & 63, wv = tid >> 6;
    const int r16 = lane & 15, quad = lane >> 4, koff = quad * 8;
    const int mbase = bx * 512 + wv * 64;

    const bf16_t* ap[4];
#pragma unroll
    for (int i = 0; i < 4; ++i)
        ap[i] = A + (size_t)(mbase + i * 16 + r16) * K + koff;
    const bf16_t* bp[4];
#pragma unroll
    for (int j = 0; j < 4; ++j)
        bp[j] = W + (size_t)(nbase + j * 16 + r16) * K + koff;

    f32x4 acc[4][4];
#pragma unroll
    for (int i = 0; i < 4; ++i)
#pragma unroll
        for (int j = 0; j < 4; ++j) acc[i][j] = (f32x4){0.f, 0.f, 0.f, 0.f};

    for (int kc = 0; kc < K32; ++kc) {
        bf16x8 a[4], b[4];
#pragma unroll
        for (int i = 0; i < 4; ++i) a[i] = *(const bf16x8*)(ap[i] + kc * 32);
#pragma unroll
        for (int j = 0; j < 4; ++j) b[j] = *(const bf16x8*)(bp[j] + kc * 32);
#pragma unroll
        for (int i = 0; i < 4; ++i)
#pragma unroll
            for (int j = 0; j < 4; ++j)
                acc[i][j] = __builtin_amdgcn_mfma_f32_16x16x32_bf16(a[i], b[j], acc[i][j], 0, 0, 0);
    }

#pragma unroll
    for (int j = 0; j < 4; ++j) {
        int col = nbase + j * 16 + r16;
        float bf = bias[col];
#pragma unroll
        for (int i = 0; i < 4; ++i) {
            int rowq = mbase + i * 16 + quad * 4;
            if (OUTMODE == 1) {
                int b = rowq >> 5, t0 = rowq & 31;
                float4 v4;
                v4.x = acc[i][j][0] + bf; v4.y = acc[i][j][1] + bf;
                v4.z = acc[i][j][2] + bf; v4.w = acc[i][j][3] + bf;
                *(float4*)((float*)Cv + ((size_t)(b * 1024) + col) * 32 + t0) = v4;
            } else {
                bf16_t* C = (bf16_t*)Cv;
#pragma unroll
                for (int q = 0; q < 4; ++q)
                    C[(size_t)(rowq + q) * N + col] = (bf16_t)(acc[i][j][q] + bf);
            }
        }
    }
}

// single-poller gate: tid0 spins (sleepy), everyone else waits at the barrier.
__device__ __forceinline__ void gate_on(int* p, int thresh) {
    if (threadIdx.x == 0) {
        while (__hip_atomic_load(p, __ATOMIC_RELAXED,
                                 __HIP_MEMORY_SCOPE_AGENT) < thresh)
            __builtin_amdgcn_s_sleep(8);
    }
    __syncthreads();
    asm volatile("" ::: "memory");
}

// ---------------------------------------------------------------------------
// Fused pipeline kernel: 880 blocks x 512 threads, 84KB LDS (real) -> 1/CU.
//   0..127   gru (R5 core + gi gate, sub-flag release)
//   128..511 giE producers (low-t-first)
//   512..703 giV producers (low-t-first)
//   704..831 OV consumers, 832..847 vrep (gate vdone==64)
//   848..879 erep consumers (gate edone==64)
// ---------------------------------------------------------------------------
__global__ __launch_bounds__(512) void fused_scan(
    bf16_t* __restrict__ giV, bf16_t* __restrict__ giE,
    const bf16_t* __restrict__ WhV, const bf16_t* __restrict__ WhE,
    const float* __restrict__ bhV, const float* __restrict__ bhE,
    bf16_t* __restrict__ hV, bf16_t* __restrict__ hE,
    bf16_t* __restrict__ hbuf, int* __restrict__ flags, int* __restrict__ gicnt,
    const int* __restrict__ ivtx, const int* __restrict__ iedg,
    const bf16_t* __restrict__ vemb, const bf16_t* __restrict__ eemb,
    const bf16_t* __restrict__ vwi, const bf16_t* __restrict__ ewi,
    const float* __restrict__ vbi, const float* __restrict__ ebi,
    const bf16_t* __restrict__ voutw, const float* __restrict__ voutb,
    const bf16_t* __restrict__ vrepw, const float* __restrict__ vrepb,
    const bf16_t* __restrict__ erepw, const float* __restrict__ erepb,
    bf16_t* __restrict__ vrep, bf16_t* __restrict__ erep,
    float* __restrict__ out)
{
    // ONE LDS object, 83968 B: hbf (33280) + red (12288) + pad. A single
    // accessed array is allocated whole -- DCE cannot shrink it (R9 lesson).
    // 83968 B/block -> 1 block/CU.
    __shared__ __align__(16) char lds_all[83968];
    bf16_t (*hbf)[520] = (bf16_t (*)[520])lds_all;             // [32][520] bf16
    f32x4 (*red)[3][64] = (f32x4 (*)[3][64])(lds_all + 33280); // [4][3][64] f32x4

    const int bid = blockIdx.x;

    if (bid >= 128) {
        if (bid < 512) {            // giE producers (384), low-t-first
            int g3 = bid - 128;
            int bx = g3 / 24, nb = g3 - bx * 24;
            produce_gi<2, 512>(ewi, ebi, giE, iedg, eemb, gicnt + 32, bx, nb * 64);
        } else if (bid < 704) {     // giV producers (192), low-t-first
            int g2 = bid - 512;
            int bx = g2 / 24, nb = g2 - bx * 24;
            produce_gi<1, 256>(vwi, vbi, giV, ivtx, vemb, gicnt, bx, nb * 64);
        } else if (bid < 848) {     // OV (128) + vrep (16): gate vdone==64
            gate_on(&gicnt[96], 64);
            if (bid < 832) {
                int cb = bid - 704;
                consume_gemm<1, 512>(hV, voutw, voutb, out, 1024, cb & 7, (cb >> 3) * 64);
            } else {
                int cb = bid - 832;
                consume_gemm<0, 512>(hV, vrepw, vrepb, vrep, 128, cb & 7, (cb >> 3) * 64);
            }
        } else {                    // erep consumers (32): gate edone==64
            gate_on(&gicnt[97], 64);
            int cb = bid - 848;
            consume_gemm<0, 512>(hE, erepw, erepb, erep, 128, cb & 15, (cb >> 4) * 64);
        }
        return;
    }

    // ---- GRU core (R5 geometry + sub-flag release): blocks 0..127 ----
    const int role = bid >> 6;           // 0 vertex (64 blocks), 1 edge (64)
    const int lb   = bid & 63;
    const int g    = lb & 7;             // batch group: rows g*16 .. g*16+15
    const int s    = lb >> 3;            // col-slice 0..7 (64 cols each)
    const bf16_t* gi = role ? giE : giV;
    const bf16_t* Wh = role ? WhE : WhV;
    const float*  bh = role ? bhE : bhV;
    bf16_t* hout = role ? hE : hV;
    const int T = role ? 64 : 32;
    const int slot = role * 8 + g;
    bf16_t* buf0 = hbuf + (size_t)slot * 16384;   // [2 parity][16 rows][512]
    int* sfl = flags + 256 + slot * 32;           // 32 per-team sub-flags/slot
    int* gc = role ? (gicnt + 32) : gicnt;
    int* done = role ? &gicnt[97] : &gicnt[96];
    const int bb = g * 16;

    const int tid = threadIdx.x, lane = tid & 63, w = tid >> 6;
    const int team = w >> 1, half = w & 1;        // team 0..3 (16-col strip), K-half 0..1
    const int r16 = lane & 15, quad = lane >> 4, koff = quad * 8;
    const int j = s * 64 + team * 16 + r16;       // this lane's h column (0..511)
    const int kbase = half * 256;                 // this wave's K-half

    // Wh K-half slice: 3 x 8 x bf16x8 = 96 regs requested; allocator remats
    // -> ~192KB/step L1 stream, 1.28us/step. Accepted: cheapest Wh transport
    // measured (R5 228 vs R7-LDS 309 vs R3-full 319).
    bf16x8 wfrag[3][8];
#pragma unroll
    for (int gate = 0; gate < 3; ++gate) {
        const bf16_t* wrow = Wh + ((size_t)(gate * 512 + j)) * 512 + kbase + koff;
#pragma unroll
        for (int kc = 0; kc < 8; ++kc)
            wfrag[gate][kc] = *(const bf16x8*)(wrow + kc * 32);
    }
    const float bhr = bh[j], bhz = bh[512 + j], bhn = bh[1024 + j];
    float hq[4] = {0.f, 0.f, 0.f, 0.f};           // live in half-0 waves

    for (int u = tid; u < 16 * 520; u += 512)
        ((bf16_t*)hbf)[u] = (bf16_t)0.f;          // h(0) = 0 (16 rows used)
    __syncthreads();

    for (int t = 0; t < T; ++t) {
        // ---- gi gate: wave0 polls gc[t] (sleepy; passes instantly once
        //      producers are ahead), everyone else waits at B1. B1 is also
        //      the iteration join (B5 removed). ----
        if (w == 0) {
            while (__hip_atomic_load(&gc[t], __ATOMIC_RELAXED,
                                     __HIP_MEMORY_SCOPE_AGENT) < 24)
                __builtin_amdgcn_s_sleep(2);
        }
        __syncthreads();                          // B1: gi[t] visible; iter join
        asm volatile("" ::: "memory");

        // gi[t] loads (half0 only), issued before the flag wait to hide latency
        float gv[3][4];
        if (half == 0) {
#pragma unroll
            for (int gg = 0; gg < 3; ++gg)
#pragma unroll
                for (int q = 0; q < 4; ++q)
                    gv[gg][q] = (float)gi[((size_t)(t * 128 + bb + quad * 4 + q)) * 1536
                                          + gg * 512 + j];
        }

        if (t > 0) {
            // h(t) handoff: wave1 polls the 32 per-team sub-flags tight
            if (w == 1) {
                while (!__all((int)(__hip_atomic_load(&sfl[lane & 31], __ATOMIC_RELAXED,
                                                      __HIP_MEMORY_SCOPE_AGENT) >= t))) { }
            }
            __syncthreads();                      // B2: sub-flags observed
            asm volatile("" ::: "memory");
            // full 16x512 h(t) from slot buffer -> LDS (4 x 8B per thread)
            ull_t* src = (ull_t*)(buf0 + (size_t)(t & 1) * 8192);
#pragma unroll
            for (int k = 0; k < 4; ++k) {
                int u = tid + k * 512;            // 2048 units: row = u>>7, 8B unit = u&127
                ull_t vv = __hip_atomic_load(src + u, __ATOMIC_RELAXED,
                                             __HIP_MEMORY_SCOPE_AGENT);
                *(ull_t*)&hbf[u >> 7][(u & 127) * 4] = vv;
            }
        }
        __syncthreads();                          // B3: h(t) complete in LDS

        // MFMA: partial gh over this wave's K-half; A from hbf, B from wfrag
        f32x4 ar = {0.f,0.f,0.f,0.f}, az = {0.f,0.f,0.f,0.f}, an = {0.f,0.f,0.f,0.f};
#pragma unroll
        for (int kc = 0; kc < 8; ++kc) {
            bf16x8 a = *(const bf16x8*)&hbf[r16][kbase + kc * 32 + koff];
            ar = __builtin_amdgcn_mfma_f32_16x16x32_bf16(a, wfrag[0][kc], ar, 0, 0, 0);
            az = __builtin_amdgcn_mfma_f32_16x16x32_bf16(a, wfrag[1][kc], az, 0, 0, 0);
            an = __builtin_amdgcn_mfma_f32_16x16x32_bf16(a, wfrag[2][kc], an, 0, 0, 0);
        }

        // K-half reduce: half1 publishes partials, half0 sums
        if (half == 1) {
            red[team][0][lane] = ar;
            red[team][1][lane] = az;
            red[team][2][lane] = an;
        }
        __syncthreads();                          // B4: partials ready
                                                  // (also fences hbf reads
                                                  //  from next-iter writes)

        bf16_t hb4[4];
        if (half == 0) {
            ar += red[team][0][lane];
            az += red[team][1][lane];
            an += red[team][2][lane];
#pragma unroll
            for (int q = 0; q < 4; ++q) {
                float r = fsigmoid(gv[0][q] + ar[q] + bhr);
                float z = fsigmoid(gv[1][q] + az[q] + bhz);
                float n = ftanh(gv[2][q] + r * (an[q] + bhn));
                float hnew = (1.0f - z) * n + z * hq[q];
                hq[q] = hnew;
                hb4[q] = (bf16_t)hnew;
            }
            if (t + 1 < T) {
                // release: own 16x16 chunk -> slot buffer; each team signals
                // its OWN sub-flag after its own drain (no barrier, no tid0).
                bf16_t* dstg = buf0 + (size_t)((t + 1) & 1) * 8192;
#pragma unroll
                for (int q = 0; q < 4; ++q)
                    __hip_atomic_store(
                        (unsigned short*)(dstg + (quad * 4 + q) * 512 + j),
                        __builtin_bit_cast(unsigned short, hb4[q]),
                        __ATOMIC_RELAXED, __HIP_MEMORY_SCOPE_AGENT);
                __builtin_amdgcn_s_waitcnt(0);
                if (lane == 0)
                    __hip_atomic_store(&sfl[s * 4 + team], t + 1,
                                       __ATOMIC_RELAXED, __HIP_MEMORY_SCOPE_AGENT);
            }
            // hout: agent-scope stores (consumers read within this kernel)
#pragma unroll
            for (int q = 0; q < 4; ++q)
                __hip_atomic_store(
                    (unsigned short*)(hout + ((size_t)((bb + quad * 4 + q) * T + t)) * 512 + j),
                    __builtin_bit_cast(unsigned short, hb4[q]),
                    __ATOMIC_RELAXED, __HIP_MEMORY_SCOPE_AGENT);
        }
        // no B5: next iteration's B1 is the join
    }

    // signal scan completion (per role; 64 blocks each)
    __builtin_amdgcn_s_waitcnt(0);
    __syncthreads();
    if (tid == 0)
        __hip_atomic_fetch_add(done, 1, __ATOMIC_RELAXED, __HIP_MEMORY_SCOPE_AGENT);
}

// O_edge_type[b,k,te] = erep[b,te,:] . etype_W[k,:] + etype_b[k]
__global__ __launch_bounds__(256) void etype_kernel(
    const bf16_t* __restrict__ erep, const float* __restrict__ W,
    const float* __restrict__ bias, float* __restrict__ out)
{
    int o = blockIdx.x * 256 + threadIdx.x;      // 65536 outputs
    int te = o & 63, k = (o >> 6) & 7, b = o >> 9;
    float sacc = bias[k];
    const bf16_t* e = erep + ((size_t)(b * 64 + te)) * 128;
    const float* w = W + k * 128;
#pragma unroll 8
    for (int r = 0; r < 128; ++r) sacc += (float)e[r] * w[r];
    out[OUT_OT + o] = sacc;
}

// O_edge[b,tv,{0,1},te] = sum_r tanh(e[b,te,r]+v[b,tv,r]) * {src,dst}_w[r] + b
__global__ __launch_bounds__(256) void attn_kernel(
    const bf16_t* __restrict__ erep, const bf16_t* __restrict__ vrep,
    const float* __restrict__ src_w, const float* __restrict__ src_b,
    const float* __restrict__ dst_w, const float* __restrict__ dst_b,
    float* __restrict__ out)
{
    int b = blockIdx.x >> 1, half = blockIdx.x & 1;
    __shared__ float es[32][129], vs[32][129], swf[128], dwf[128];
    int tid = threadIdx.x;
    for (int f = tid; f < 32 * 128; f += 256) {
        int i = f >> 7, r = f & 127;
        es[i][r] = (float)erep[((size_t)(b * 64 + half * 32 + i)) * 128 + r];
        vs[i][r] = (float)vrep[((size_t)(b * 32 + i)) * 128 + r];
    }
    if (tid < 128) { swf[tid] = src_w[tid]; dwf[tid] = dst_w[tid]; }
    __syncthreads();
    float sb = src_b[0], db = dst_b[0];
    for (int p = tid; p < 1024; p += 256) {
        int te = p & 31, tv = p >> 5;
        float sacc = 0.f, dacc = 0.f;
#pragma unroll 4
        for (int r = 0; r < 128; ++r) {
            float u = ftanh(es[te][r] + vs[tv][r]);
            sacc += u * swf[r];
            dacc += u * dwf[r];
        }
        int teg = half * 32 + te;
        size_t base = OUT_OE + ((size_t)(b * 32 + tv) * 2) * 64;
        out[base + teg]      = sacc + sb;
        out[base + 64 + teg] = dacc + db;
    }
}

extern "C" void kernel_launch(void* const* d_in, const int* in_sizes, int n_in,
                              void* d_out, int out_size, void* d_ws, size_t ws_size,
                              hipStream_t stream)
{
    const int*   input_vertex = (const int*)d_in[0];
    const int*   input_edge   = (const int*)d_in[1];
    const float* vertex_emb   = (const float*)d_in[2];
    const float* v_Wi  = (const float*)d_in[3];
    const float* v_Wh  = (const float*)d_in[4];
    const float* v_bi  = (const float*)d_in[5];
    const float* v_bh  = (const float*)d_in[6];
    const float* vout_W = (const float*)d_in[7];
    const float* vout_b = (const float*)d_in[8];
    const float* vrep_W = (const float*)d_in[9];
    const float* vrep_b = (const float*)d_in[10];
    const float* edge_emb = (const float*)d_in[11];
    const float* e_Wi  = (const float*)d_in[12];
    const float* e_Wh  = (const float*)d_in[13];
    const float* e_bi  = (const float*)d_in[14];
    const float* e_bh  = (const float*)d_in[15];
    const float* erep_W = (const float*)d_in[16];
    const float* erep_b = (const float*)d_in[17];
    const float* etype_W = (const float*)d_in[18];
    const float* etype_b = (const float*)d_in[19];
    const float* src_w = (const float*)d_in[20];
    const float* src_b = (const float*)d_in[21];
    const float* dst_w = (const float*)d_in[22];
    const float* dst_b = (const float*)d_in[23];

    bf16_t* ws   = (bf16_t*)d_ws;
    bf16_t* giV  = ws + OFF_GIV;
    bf16_t* giE  = ws + OFF_GIE;
    bf16_t* hV   = ws + OFF_HV;
    bf16_t* hE   = ws + OFF_HE;
    bf16_t* vrep = ws + OFF_VREP;
    bf16_t* erep = ws + OFF_EREP;
    bf16_t* hbuf = ws + OFF_HBUF;
    bf16_t* cvt  = ws + OFF_CVT;
    int*    flags = (int*)((char*)d_ws + FLAG_BYTE_OFF);
    int*    gicnt = (int*)((char*)d_ws + GICNT_BYTE_OFF);
    float*  out  = (float*)d_out;

    // zero the 4KB control region (legacy flags + gicnt + sub-flags + slack);
    // ends exactly at cvt. Capture-safe (R13-proven).
    hipMemsetAsync((char*)d_ws + FLAG_BYTE_OFF, 0, 4096, stream);

    // 1) downcast weights to bf16
    prep_kernel<<<3592, 256, 0, stream>>>(vertex_emb, edge_emb, v_Wi, e_Wi, v_Wh, e_Wh,
                                          vout_W, vrep_W, erep_W, cvt);

    // 2) fused pipeline: scans + gi producers + OV/vrep/erep consumers
    fused_scan<<<880, 512, 0, stream>>>(
        giV, giE, cvt + CVT_VWH, cvt + CVT_EWH, v_bh, e_bh, hV, hE,
        hbuf, flags, gicnt, input_vertex, input_edge,
        cvt + CVT_VEMB, cvt + CVT_EEMB, cvt + CVT_VWI, cvt + CVT_EWI,
        v_bi, e_bi,
        cvt + CVT_VOUT, vout_b, cvt + CVT_VREPW, vrep_b,
        cvt + CVT_EREPW, erep_b, vrep, erep, out);

    // 3) epilogues
    etype_kernel<<<256, 256, 0, stream>>>(erep, etype_W, etype_b, out);
    attn_kernel<<<256, 256, 0, stream>>>(erep, vrep, src_w, src_b, dst_w, dst_b, out);
}